// Round 1
// baseline (1742.439 us; speedup 1.0000x reference)
//
#include <hip/hip_runtime.h>

#define N_NODES 100000
#define N_EDGES 300000
#define N_ETOT  400000   // E + N self-loops
#define NGRAPH  4096
#define HID     128
#define GROWS   4

// ---------------- utility ----------------
__global__ void fill_kernel(float* __restrict__ p, int n, float v) {
    int i = blockIdx.x * blockDim.x + threadIdx.x;
    if (i < n) p[i] = v;
}

// ---------------- GEMM + attention scores ----------------
// h = X[N,K] @ W[K,128]; al_s[n,h] = sum_c h[n,h,c]*as[h,c]; same for al_d.
// One block = 128 threads handles GROWS rows. W staged in LDS in K-tiles of 64.
__global__ __launch_bounds__(128) void gemm_scores_kernel(
    const float* __restrict__ X, const float* __restrict__ W,
    const float* __restrict__ avs, const float* __restrict__ avd,
    float* __restrict__ Hout, float* __restrict__ als, float* __restrict__ ald,
    int K, int Hh, int C)
{
    __shared__ float Wl[64 * HID];       // 32 KB
    __shared__ float Xl[GROWS * 64];     // 1 KB, layout [k][r]
    __shared__ float reds[HID], redd[HID];

    const int tid  = threadIdx.x;
    const int row0 = blockIdx.x * GROWS;

    float acc[GROWS] = {0.f, 0.f, 0.f, 0.f};

    for (int k0 = 0; k0 < K; k0 += 64) {
        const int kt = min(64, K - k0);
        for (int i = tid; i < kt * HID; i += 128)
            Wl[i] = W[k0 * HID + i];
        for (int i = tid; i < GROWS * kt; i += 128) {
            int k = i >> 2, r = i & 3;
            int row = row0 + r;
            Xl[i] = (row < N_NODES) ? X[(size_t)row * K + k0 + k] : 0.f;
        }
        __syncthreads();
        for (int k = 0; k < kt; ++k) {
            float wv = Wl[k * HID + tid];
            const float4 xv = *(const float4*)&Xl[k * 4];
            acc[0] += xv.x * wv;
            acc[1] += xv.y * wv;
            acc[2] += xv.z * wv;
            acc[3] += xv.w * wv;
        }
        __syncthreads();
    }

    const float as_v = avs[tid];
    const float ad_v = avd[tid];
    for (int r = 0; r < GROWS; ++r) {
        int row = row0 + r;
        if (row >= N_NODES) break;   // uniform per block
        Hout[(size_t)row * HID + tid] = acc[r];
        reds[tid] = acc[r] * as_v;
        redd[tid] = acc[r] * ad_v;
        __syncthreads();
        if (tid < Hh) {
            float s = 0.f, d = 0.f;
            for (int c = 0; c < C; ++c) { s += reds[tid * C + c]; d += redd[tid * C + c]; }
            als[row * Hh + tid] = s;
            ald[row * Hh + tid] = d;
        }
        __syncthreads();
    }
}

// ---------------- edge pass 1: exp(leaky_relu(score)), accumulate denominator ----------------
__global__ void edge_ex_kernel(
    const float* __restrict__ als, const float* __restrict__ ald,
    const int* __restrict__ ei, float* __restrict__ exb,
    float* __restrict__ den, int Hh, int hsh)
{
    int i = blockIdx.x * blockDim.x + threadIdx.x;
    if (i >= N_ETOT * Hh) return;
    int e = i >> hsh;
    int h = i & (Hh - 1);
    int src, dst;
    if (e < N_EDGES) { src = ei[e]; dst = ei[N_EDGES + e]; }
    else             { src = dst = e - N_EDGES; }
    float v = als[src * Hh + h] + ald[dst * Hh + h];
    v = (v > 0.f) ? v : 0.2f * v;
    float ex = expf(v);
    exb[i] = ex;
    atomicAdd(&den[dst * Hh + h], ex);
}

// ---------------- edge pass 2: out[dst] += h[src] * alpha ----------------
__global__ void edge_agg_kernel(
    const float* __restrict__ Hbuf, const float* __restrict__ exb,
    const float* __restrict__ den, const int* __restrict__ ei,
    float* __restrict__ Out, int Hh, int csh)
{
    int i = blockIdx.x * blockDim.x + threadIdx.x;
    if (i >= N_ETOT * HID) return;
    int e = i >> 7;
    int c = i & 127;
    int h = c >> csh;
    int src, dst;
    if (e < N_EDGES) { src = ei[e]; dst = ei[N_EDGES + e]; }
    else             { src = dst = e - N_EDGES; }
    float alpha = exb[e * Hh + h] / (den[dst * Hh + h] + 1e-16f);
    atomicAdd(&Out[(size_t)dst * HID + c], Hbuf[(size_t)src * HID + c] * alpha);
}

// ---------------- BN stats ----------------
__global__ __launch_bounds__(256) void bn_stats_kernel(
    const float* __restrict__ X, float* __restrict__ sums, float* __restrict__ ssq)
{
    __shared__ float ls[256], lq[256];
    int tid = threadIdx.x;
    int c = tid & 127;
    int half = tid >> 7;
    int rpb = (N_NODES + gridDim.x - 1) / gridDim.x;
    int r0 = blockIdx.x * rpb;
    int r1 = min(r0 + rpb, N_NODES);
    float s = 0.f, q = 0.f;
    for (int r = r0 + half; r < r1; r += 2) {
        float v = X[(size_t)r * HID + c];
        s += v; q += v * v;
    }
    ls[tid] = s; lq[tid] = q;
    __syncthreads();
    if (half == 0) {
        s = ls[tid] + ls[tid + 128];
        q = lq[tid] + lq[tid + 128];
        atomicAdd(&sums[c], s);
        atomicAdd(&ssq[c], q);
    }
}

__global__ void bn_finalize_kernel(
    const float* __restrict__ sums, const float* __restrict__ ssq,
    const float* __restrict__ g, const float* __restrict__ be,
    float* __restrict__ scale, float* __restrict__ shift)
{
    int c = threadIdx.x;
    float m = sums[c] * (1.f / N_NODES);
    float v = ssq[c] * (1.f / N_NODES) - m * m;
    float sc = g[c] * rsqrtf(v + 1e-5f);
    scale[c] = sc;
    shift[c] = be[c] - m * sc;
}

__global__ void bn_apply_kernel(
    float* __restrict__ X, const float* __restrict__ scale, const float* __restrict__ shift)
{
    int i = blockIdx.x * blockDim.x + threadIdx.x;
    if (i >= N_NODES * HID) return;
    int c = i & 127;
    float v = X[i] * scale[c] + shift[c];
    X[i] = (v > 0.f) ? v : 0.f;
}

// ---------------- global mean pool ----------------
__global__ void pool_kernel(
    const float* __restrict__ X, const int* __restrict__ batch,
    float* __restrict__ pooled, float* __restrict__ cnt)
{
    int i = blockIdx.x * blockDim.x + threadIdx.x;
    if (i >= N_NODES * HID) return;
    int n = i >> 7;
    int c = i & 127;
    int g = batch[n];
    atomicAdd(&pooled[(size_t)g * HID + c], X[i]);
    if (c == 0) atomicAdd(&cnt[g], 1.0f);
}

// ---------------- MLP head ----------------
__global__ __launch_bounds__(64) void mlp_kernel(
    const float* __restrict__ pooled, const float* __restrict__ cnt,
    const float* __restrict__ fw1, const float* __restrict__ fb1,
    const float* __restrict__ fw2, const float* __restrict__ fb2,
    float* __restrict__ out)
{
    __shared__ float row[HID];
    int g = blockIdx.x;
    int j = threadIdx.x;
    float inv = 1.0f / fmaxf(cnt[g], 1.0f);
    row[j]      = pooled[(size_t)g * HID + j] * inv;
    row[j + 64] = pooled[(size_t)g * HID + 64 + j] * inv;
    __syncthreads();
    float z = fb1[j];
    for (int c = 0; c < HID; ++c) z += row[c] * fw1[c * 64 + j];
    z = fmaxf(z, 0.f);
    float p = z * fw2[j];
    for (int off = 32; off > 0; off >>= 1) p += __shfl_down(p, off);
    if (j == 0) out[g] = p + fb2[0];
}

// ---------------- host ----------------
extern "C" void kernel_launch(void* const* d_in, const int* in_sizes, int n_in,
                              void* d_out, int out_size, void* d_ws, size_t ws_size,
                              hipStream_t stream)
{
    const float* x     = (const float*)d_in[0];
    const int*   ei    = (const int*)d_in[1];
    const int*   batch = (const int*)d_in[2];
    const float* W1  = (const float*)d_in[3];
    const float* as1 = (const float*)d_in[4];
    const float* ad1 = (const float*)d_in[5];
    // b1 (d_in[6]) cancels through BN — skipped
    const float* g1  = (const float*)d_in[7];
    const float* be1 = (const float*)d_in[8];
    const float* W2  = (const float*)d_in[9];
    const float* as2 = (const float*)d_in[10];
    const float* ad2 = (const float*)d_in[11];
    const float* g2  = (const float*)d_in[13];
    const float* be2 = (const float*)d_in[14];
    const float* W3  = (const float*)d_in[15];
    const float* as3 = (const float*)d_in[16];
    const float* ad3 = (const float*)d_in[17];
    const float* g3  = (const float*)d_in[19];
    const float* be3 = (const float*)d_in[20];
    const float* fw1 = (const float*)d_in[21];
    const float* fb1 = (const float*)d_in[22];
    const float* fw2 = (const float*)d_in[23];
    const float* fb2 = (const float*)d_in[24];
    float* out = (float*)d_out;

    float* ws = (float*)d_ws;
    const size_t NH = (size_t)N_NODES * HID;
    float* A      = ws;                               // h buffer
    float* B      = A + NH;                           // aggregated / normalized buffer
    float* als    = B + NH;
    float* ald    = als + (size_t)N_NODES * 4;
    float* den    = ald + (size_t)N_NODES * 4;
    float* exb    = den + (size_t)N_NODES * 4;
    float* sums   = exb + (size_t)N_ETOT * 4;
    float* ssq    = sums + HID;
    float* scale  = ssq + HID;
    float* shift  = scale + HID;
    float* pooled = shift + HID;
    float* cnt    = pooled + (size_t)NGRAPH * HID;

    auto cdiv = [](int a, int b) { return (a + b - 1) / b; };

    auto layer = [&](const float* in, int K,
                     const float* W, const float* avs, const float* avd,
                     const float* g, const float* be,
                     int Hh, int hsh, int C, int csh)
    {
        gemm_scores_kernel<<<cdiv(N_NODES, GROWS), 128, 0, stream>>>(
            in, W, avs, avd, A, als, ald, K, Hh, C);
        fill_kernel<<<cdiv(N_NODES * HID, 256), 256, 0, stream>>>(B, N_NODES * HID, 0.f);
        fill_kernel<<<cdiv(N_NODES * Hh, 256), 256, 0, stream>>>(den, N_NODES * Hh, 0.f);
        edge_ex_kernel<<<cdiv(N_ETOT * Hh, 256), 256, 0, stream>>>(als, ald, ei, exb, den, Hh, hsh);
        edge_agg_kernel<<<cdiv(N_ETOT * HID, 256), 256, 0, stream>>>(A, exb, den, ei, B, Hh, csh);
        fill_kernel<<<1, 256, 0, stream>>>(sums, 256, 0.f);  // sums + ssq contiguous
        bn_stats_kernel<<<256, 256, 0, stream>>>(B, sums, ssq);
        bn_finalize_kernel<<<1, 128, 0, stream>>>(sums, ssq, g, be, scale, shift);
        bn_apply_kernel<<<cdiv(N_NODES * HID, 256), 256, 0, stream>>>(B, scale, shift);
    };

    layer(x, 22,  W1, as1, ad1, g1, be1, 4, 2, 32, 5);
    layer(B, 128, W2, as2, ad2, g2, be2, 4, 2, 32, 5);
    layer(B, 128, W3, as3, ad3, g3, be3, 1, 0, 128, 7);

    fill_kernel<<<cdiv(NGRAPH * HID + NGRAPH, 256), 256, 0, stream>>>(pooled, NGRAPH * HID + NGRAPH, 0.f);
    pool_kernel<<<cdiv(N_NODES * HID, 256), 256, 0, stream>>>(B, batch, pooled, cnt);
    mlp_kernel<<<NGRAPH, 64, 0, stream>>>(pooled, cnt, fw1, fb1, fw2, fb2, out);
}

// Round 2
// 1229.398 us; speedup vs baseline: 1.4173x; 1.4173x over previous
//
#include <hip/hip_runtime.h>

#define N_NODES 100000
#define N_EDGES 300000
#define N_ETOT  400000   // E + N self-loops
#define NGRAPH  4096
#define HID     128

// ---------------- GEMM: C[M,128] = A[M,K] @ W[K,128] ----------------
// 256 threads, 128-row tile, 8x8 micro-tile per thread (2x2 groups of float4).
template<int K>
__global__ __launch_bounds__(256) void gemm128_kernel(
    const float* __restrict__ A, const float* __restrict__ W,
    float* __restrict__ C, int M)
{
    __shared__ float Al[32][HID];   // [k][row]
    __shared__ float Wl[32][HID];   // [k][col]
    const int tid = threadIdx.x;
    const int tx = tid & 15;
    const int ty = tid >> 4;
    const int row0 = blockIdx.x * 128;

    float acc[2][2][4][4];          // [rowhalf][colhalf][i][j]
    #pragma unroll
    for (int a = 0; a < 2; ++a)
      #pragma unroll
      for (int b = 0; b < 2; ++b)
        #pragma unroll
        for (int i = 0; i < 4; ++i)
          #pragma unroll
          for (int j = 0; j < 4; ++j) acc[a][b][i][j] = 0.f;

    for (int k0 = 0; k0 < K; k0 += 32) {
        // ---- stage W tile: Wl[k][col], conflict-free col mapping ----
        {
            const int k  = tid >> 3;        // 0..31
            const int c0 = (tid & 7) * 4;   // 0..28
            if (k0 + k < K) {
                #pragma unroll
                for (int q = 0; q < 4; ++q)
                    *(float4*)&Wl[k][c0 + 32*q] =
                        *(const float4*)&W[(size_t)(k0 + k)*HID + c0 + 32*q];
            } else {
                #pragma unroll
                for (int q = 0; q < 4; ++q)
                    *(float4*)&Wl[k][c0 + 32*q] = make_float4(0.f,0.f,0.f,0.f);
            }
        }
        // ---- stage A tile transposed: Al[k][row] ----
        {
            const int r    = tid >> 1;          // 0..127
            const int kh   = (tid & 1) * 16;    // 0 or 16
            const int grow = row0 + r;
            if constexpr (K % 32 == 0) {
                if (grow < M) {
                    #pragma unroll
                    for (int q = 0; q < 4; ++q) {
                        const float4 v = *(const float4*)&A[(size_t)grow*K + k0 + kh + 4*q];
                        Al[kh+4*q+0][r] = v.x;
                        Al[kh+4*q+1][r] = v.y;
                        Al[kh+4*q+2][r] = v.z;
                        Al[kh+4*q+3][r] = v.w;
                    }
                } else {
                    #pragma unroll
                    for (int q = 0; q < 16; ++q) Al[kh+q][r] = 0.f;
                }
            } else {
                #pragma unroll
                for (int q = 0; q < 16; ++q) {
                    const int k = kh + q;
                    float v = 0.f;
                    if (grow < M && k0 + k < K) v = A[(size_t)grow*K + k0 + k];
                    Al[k][r] = v;
                }
            }
        }
        __syncthreads();
        #pragma unroll 4
        for (int k = 0; k < 32; ++k) {
            const float4 a0 = *(const float4*)&Al[k][ty*4];
            const float4 a1 = *(const float4*)&Al[k][64 + ty*4];
            const float4 w0 = *(const float4*)&Wl[k][tx*4];
            const float4 w1 = *(const float4*)&Wl[k][64 + tx*4];
            const float av[2][4] = {{a0.x,a0.y,a0.z,a0.w},{a1.x,a1.y,a1.z,a1.w}};
            const float wv[2][4] = {{w0.x,w0.y,w0.z,w0.w},{w1.x,w1.y,w1.z,w1.w}};
            #pragma unroll
            for (int rh = 0; rh < 2; ++rh)
              #pragma unroll
              for (int ch = 0; ch < 2; ++ch)
                #pragma unroll
                for (int i = 0; i < 4; ++i)
                  #pragma unroll
                  for (int j = 0; j < 4; ++j)
                      acc[rh][ch][i][j] += av[rh][i] * wv[ch][j];
        }
        __syncthreads();
    }
    #pragma unroll
    for (int rh = 0; rh < 2; ++rh)
      #pragma unroll
      for (int i = 0; i < 4; ++i) {
        const int grow = row0 + rh*64 + ty*4 + i;
        if (grow < M) {
            #pragma unroll
            for (int ch = 0; ch < 2; ++ch) {
                *(float4*)&C[(size_t)grow*HID + ch*64 + tx*4] =
                    make_float4(acc[rh][ch][i][0], acc[rh][ch][i][1],
                                acc[rh][ch][i][2], acc[rh][ch][i][3]);
            }
        }
      }
}

// ---------------- attention scores: als/ald[n,h] = sum_c h[n,h,c]*a[h,c] ----------------
__global__ __launch_bounds__(256) void scores_kernel(
    const float* __restrict__ H, const float* __restrict__ avs, const float* __restrict__ avd,
    float* __restrict__ als, float* __restrict__ ald, int Hh)
{
    __shared__ float ps[2][4], pd[2][4];
    const int tid = threadIdx.x;
    const int ln  = tid & 127;     // channel
    const int nl  = tid >> 7;      // node slot in block
    const int node = blockIdx.x * 2 + nl;
    const float v = H[(size_t)node * HID + ln];
    float s = v * avs[ln];
    float d = v * avd[ln];
    for (int off = 16; off; off >>= 1) {
        s += __shfl_down(s, off);
        d += __shfl_down(d, off);
    }
    if ((tid & 31) == 0) { ps[nl][ln >> 5] = s; pd[nl][ln >> 5] = d; }
    __syncthreads();
    if (ln < Hh) {
        if (Hh == 4) {
            als[node*4 + ln] = ps[nl][ln];
            ald[node*4 + ln] = pd[nl][ln];
        } else {
            als[node] = ps[nl][0] + ps[nl][1] + ps[nl][2] + ps[nl][3];
            ald[node] = pd[nl][0] + pd[nl][1] + pd[nl][2] + pd[nl][3];
        }
    }
}

// ---------------- edge pass 1: exp(leaky_relu(score)), accumulate denominator ----------------
__global__ void edge_ex_kernel(
    const float* __restrict__ als, const float* __restrict__ ald,
    const int* __restrict__ ei, float* __restrict__ exb,
    float* __restrict__ den, int Hh, int hsh)
{
    int i = blockIdx.x * blockDim.x + threadIdx.x;
    if (i >= N_ETOT * Hh) return;
    int e = i >> hsh;
    int h = i & (Hh - 1);
    int src, dst;
    if (e < N_EDGES) { src = ei[e]; dst = ei[N_EDGES + e]; }
    else             { src = dst = e - N_EDGES; }
    float v = als[src * Hh + h] + ald[dst * Hh + h];
    v = (v > 0.f) ? v : 0.2f * v;
    float ex = expf(v);
    exb[i] = ex;
    atomicAdd(&den[dst * Hh + h], ex);
}

// ---------------- normalize: exb -> alpha ----------------
__global__ void alpha_kernel(
    float* __restrict__ exb, const float* __restrict__ den,
    const int* __restrict__ ei, int Hh, int hsh)
{
    int i = blockIdx.x * blockDim.x + threadIdx.x;
    if (i >= N_ETOT * Hh) return;
    int e = i >> hsh;
    int h = i & (Hh - 1);
    int dst = (e < N_EDGES) ? ei[N_EDGES + e] : e - N_EDGES;
    exb[i] = exb[i] / (den[dst * Hh + h] + 1e-16f);
}

// ---------------- edge pass 2: out[dst] += h[src] * alpha ----------------
__global__ void edge_agg_kernel(
    const float* __restrict__ Hbuf, const float* __restrict__ alpha,
    const int* __restrict__ ei, float* __restrict__ Out, int Hh, int csh)
{
    int i = blockIdx.x * blockDim.x + threadIdx.x;
    if (i >= N_ETOT * HID) return;
    int e = i >> 7;
    int c = i & 127;
    int h = c >> csh;
    int src, dst;
    if (e < N_EDGES) { src = ei[e]; dst = ei[N_EDGES + e]; }
    else             { src = dst = e - N_EDGES; }
    atomicAdd(&Out[(size_t)dst * HID + c], Hbuf[(size_t)src * HID + c] * alpha[e * Hh + h]);
}

// ---------------- BN stats ----------------
__global__ __launch_bounds__(256) void bn_stats_kernel(
    const float* __restrict__ X, float* __restrict__ sums, float* __restrict__ ssq)
{
    __shared__ float ls[256], lq[256];
    int tid = threadIdx.x;
    int c = tid & 127;
    int half = tid >> 7;
    int rpb = (N_NODES + gridDim.x - 1) / gridDim.x;
    int r0 = blockIdx.x * rpb;
    int r1 = min(r0 + rpb, N_NODES);
    float s = 0.f, q = 0.f;
    for (int r = r0 + half; r < r1; r += 2) {
        float v = X[(size_t)r * HID + c];
        s += v; q += v * v;
    }
    ls[tid] = s; lq[tid] = q;
    __syncthreads();
    if (half == 0) {
        atomicAdd(&sums[c], ls[tid] + ls[tid + 128]);
        atomicAdd(&ssq[c],  lq[tid] + lq[tid + 128]);
    }
}

__global__ void bn_finalize_kernel(
    const float* __restrict__ sums, const float* __restrict__ ssq,
    const float* __restrict__ g, const float* __restrict__ be,
    float* __restrict__ scale, float* __restrict__ shift)
{
    int c = threadIdx.x;
    float m = sums[c] * (1.f / N_NODES);
    float v = ssq[c] * (1.f / N_NODES) - m * m;
    float sc = g[c] * rsqrtf(v + 1e-5f);
    scale[c] = sc;
    shift[c] = be[c] - m * sc;
}

__global__ void bn_apply_kernel(
    float* __restrict__ X, const float* __restrict__ scale, const float* __restrict__ shift)
{
    int i = blockIdx.x * blockDim.x + threadIdx.x;
    if (i >= N_NODES * HID) return;
    int c = i & 127;
    float v = X[i] * scale[c] + shift[c];
    X[i] = (v > 0.f) ? v : 0.f;
}

// ---------------- global mean pool ----------------
__global__ void pool_kernel(
    const float* __restrict__ X, const int* __restrict__ batch,
    float* __restrict__ pooled, float* __restrict__ cnt)
{
    int i = blockIdx.x * blockDim.x + threadIdx.x;
    if (i >= N_NODES * HID) return;
    int n = i >> 7;
    int c = i & 127;
    int g = batch[n];
    atomicAdd(&pooled[(size_t)g * HID + c], X[i]);
    if (c == 0) atomicAdd(&cnt[g], 1.0f);
}

// ---------------- MLP head ----------------
__global__ __launch_bounds__(64) void mlp_kernel(
    const float* __restrict__ pooled, const float* __restrict__ cnt,
    const float* __restrict__ fw1, const float* __restrict__ fb1,
    const float* __restrict__ fw2, const float* __restrict__ fb2,
    float* __restrict__ out)
{
    __shared__ float row[HID];
    int g = blockIdx.x;
    int j = threadIdx.x;
    float inv = 1.0f / fmaxf(cnt[g], 1.0f);
    row[j]      = pooled[(size_t)g * HID + j] * inv;
    row[j + 64] = pooled[(size_t)g * HID + 64 + j] * inv;
    __syncthreads();
    float z = fb1[j];
    for (int c = 0; c < HID; ++c) z += row[c] * fw1[c * 64 + j];
    z = fmaxf(z, 0.f);
    float p = z * fw2[j];
    for (int off = 32; off > 0; off >>= 1) p += __shfl_down(p, off);
    if (j == 0) out[g] = p + fb2[0];
}

// ---------------- host ----------------
extern "C" void kernel_launch(void* const* d_in, const int* in_sizes, int n_in,
                              void* d_out, int out_size, void* d_ws, size_t ws_size,
                              hipStream_t stream)
{
    const float* x     = (const float*)d_in[0];
    const int*   ei    = (const int*)d_in[1];
    const int*   batch = (const int*)d_in[2];
    const float* W1  = (const float*)d_in[3];
    const float* as1 = (const float*)d_in[4];
    const float* ad1 = (const float*)d_in[5];
    const float* g1  = (const float*)d_in[7];
    const float* be1 = (const float*)d_in[8];
    const float* W2  = (const float*)d_in[9];
    const float* as2 = (const float*)d_in[10];
    const float* ad2 = (const float*)d_in[11];
    const float* g2  = (const float*)d_in[13];
    const float* be2 = (const float*)d_in[14];
    const float* W3  = (const float*)d_in[15];
    const float* as3 = (const float*)d_in[16];
    const float* ad3 = (const float*)d_in[17];
    const float* g3  = (const float*)d_in[19];
    const float* be3 = (const float*)d_in[20];
    const float* fw1 = (const float*)d_in[21];
    const float* fb1 = (const float*)d_in[22];
    const float* fw2 = (const float*)d_in[23];
    const float* fb2 = (const float*)d_in[24];
    float* out = (float*)d_out;

    float* ws = (float*)d_ws;
    const size_t NH = (size_t)N_NODES * HID;
    float* A      = ws;                               // h buffer
    float* B      = A + NH;                           // aggregated / normalized buffer
    float* als    = B + NH;
    float* ald    = als + (size_t)N_NODES * 4;
    float* den    = ald + (size_t)N_NODES * 4;
    float* exb    = den + (size_t)N_NODES * 4;
    float* sums   = exb + (size_t)N_ETOT * 4;
    float* ssq    = sums + HID;
    float* scale  = ssq + HID;
    float* shift  = scale + HID;
    float* pooled = shift + HID;
    float* cnt    = pooled + (size_t)NGRAPH * HID;

    auto cdiv = [](int a, int b) { return (a + b - 1) / b; };

    auto layer = [&](const float* in, const float* W, const float* avs, const float* avd,
                     const float* g, const float* be,
                     int Hh, int hsh, int csh, int K)
    {
        if (K == 128)
            gemm128_kernel<128><<<cdiv(N_NODES,128), 256, 0, stream>>>(in, W, A, N_NODES);
        else
            gemm128_kernel<22><<<cdiv(N_NODES,128), 256, 0, stream>>>(in, W, A, N_NODES);
        scores_kernel<<<cdiv(N_NODES,2), 256, 0, stream>>>(A, avs, avd, als, ald, Hh);
        hipMemsetAsync(B, 0, NH * sizeof(float), stream);
        hipMemsetAsync(den, 0, (size_t)N_NODES * Hh * sizeof(float), stream);
        edge_ex_kernel<<<cdiv(N_ETOT * Hh, 256), 256, 0, stream>>>(als, ald, ei, exb, den, Hh, hsh);
        alpha_kernel<<<cdiv(N_ETOT * Hh, 256), 256, 0, stream>>>(exb, den, ei, Hh, hsh);
        edge_agg_kernel<<<cdiv(N_ETOT * HID, 256), 256, 0, stream>>>(A, exb, ei, B, Hh, csh);
        hipMemsetAsync(sums, 0, 2 * HID * sizeof(float), stream);
        bn_stats_kernel<<<256, 256, 0, stream>>>(B, sums, ssq);
        bn_finalize_kernel<<<1, 128, 0, stream>>>(sums, ssq, g, be, scale, shift);
        bn_apply_kernel<<<cdiv(N_NODES * HID, 256), 256, 0, stream>>>(B, scale, shift);
    };

    layer(x, W1, as1, ad1, g1, be1, 4, 2, 5, 22);
    layer(B, W2, as2, ad2, g2, be2, 4, 2, 5, 128);
    layer(B, W3, as3, ad3, g3, be3, 1, 0, 7, 128);

    hipMemsetAsync(pooled, 0, ((size_t)NGRAPH * HID + NGRAPH) * sizeof(float), stream);
    pool_kernel<<<cdiv(N_NODES * HID, 256), 256, 0, stream>>>(B, batch, pooled, cnt);
    mlp_kernel<<<NGRAPH, 64, 0, stream>>>(pooled, cnt, fw1, fb1, fw2, fb2, out);
}

// Round 3
// 902.375 us; speedup vs baseline: 1.9309x; 1.3624x over previous
//
#include <hip/hip_runtime.h>

#define N_NODES 100000
#define N_EDGES 300000
#define N_ETOT  400000   // E + N self-loops
#define NGRAPH  4096
#define HID     128
#define NBLK_SCAN 391    // cdiv(N_NODES, 256)

// ---------------- GEMM: C[M,128] = A[M,K] @ W[K,128] ----------------
template<int K>
__global__ __launch_bounds__(256) void gemm128_kernel(
    const float* __restrict__ A, const float* __restrict__ W,
    float* __restrict__ C, int M)
{
    __shared__ float Al[32][HID];   // [k][row]
    __shared__ float Wl[32][HID];   // [k][col]
    const int tid = threadIdx.x;
    const int tx = tid & 15;
    const int ty = tid >> 4;
    const int row0 = blockIdx.x * 128;

    float acc[2][2][4][4];
    #pragma unroll
    for (int a = 0; a < 2; ++a)
      #pragma unroll
      for (int b = 0; b < 2; ++b)
        #pragma unroll
        for (int i = 0; i < 4; ++i)
          #pragma unroll
          for (int j = 0; j < 4; ++j) acc[a][b][i][j] = 0.f;

    for (int k0 = 0; k0 < K; k0 += 32) {
        {
            const int k  = tid >> 3;
            const int c0 = (tid & 7) * 4;
            if (k0 + k < K) {
                #pragma unroll
                for (int q = 0; q < 4; ++q)
                    *(float4*)&Wl[k][c0 + 32*q] =
                        *(const float4*)&W[(size_t)(k0 + k)*HID + c0 + 32*q];
            } else {
                #pragma unroll
                for (int q = 0; q < 4; ++q)
                    *(float4*)&Wl[k][c0 + 32*q] = make_float4(0.f,0.f,0.f,0.f);
            }
        }
        {
            const int r    = tid >> 1;
            const int kh   = (tid & 1) * 16;
            const int grow = row0 + r;
            if constexpr (K % 32 == 0) {
                if (grow < M) {
                    #pragma unroll
                    for (int q = 0; q < 4; ++q) {
                        const float4 v = *(const float4*)&A[(size_t)grow*K + k0 + kh + 4*q];
                        Al[kh+4*q+0][r] = v.x;
                        Al[kh+4*q+1][r] = v.y;
                        Al[kh+4*q+2][r] = v.z;
                        Al[kh+4*q+3][r] = v.w;
                    }
                } else {
                    #pragma unroll
                    for (int q = 0; q < 16; ++q) Al[kh+q][r] = 0.f;
                }
            } else {
                #pragma unroll
                for (int q = 0; q < 16; ++q) {
                    const int k = kh + q;
                    float v = 0.f;
                    if (grow < M && k0 + k < K) v = A[(size_t)grow*K + k0 + k];
                    Al[k][r] = v;
                }
            }
        }
        __syncthreads();
        #pragma unroll 4
        for (int k = 0; k < 32; ++k) {
            const float4 a0 = *(const float4*)&Al[k][ty*4];
            const float4 a1 = *(const float4*)&Al[k][64 + ty*4];
            const float4 w0 = *(const float4*)&Wl[k][tx*4];
            const float4 w1 = *(const float4*)&Wl[k][64 + tx*4];
            const float av[2][4] = {{a0.x,a0.y,a0.z,a0.w},{a1.x,a1.y,a1.z,a1.w}};
            const float wv[2][4] = {{w0.x,w0.y,w0.z,w0.w},{w1.x,w1.y,w1.z,w1.w}};
            #pragma unroll
            for (int rh = 0; rh < 2; ++rh)
              #pragma unroll
              for (int ch = 0; ch < 2; ++ch)
                #pragma unroll
                for (int i = 0; i < 4; ++i)
                  #pragma unroll
                  for (int j = 0; j < 4; ++j)
                      acc[rh][ch][i][j] += av[rh][i] * wv[ch][j];
        }
        __syncthreads();
    }
    #pragma unroll
    for (int rh = 0; rh < 2; ++rh)
      #pragma unroll
      for (int i = 0; i < 4; ++i) {
        const int grow = row0 + rh*64 + ty*4 + i;
        if (grow < M) {
            #pragma unroll
            for (int ch = 0; ch < 2; ++ch)
                *(float4*)&C[(size_t)grow*HID + ch*64 + tx*4] =
                    make_float4(acc[rh][ch][i][0], acc[rh][ch][i][1],
                                acc[rh][ch][i][2], acc[rh][ch][i][3]);
        }
      }
}

// ---------------- attention scores ----------------
__global__ __launch_bounds__(256) void scores_kernel(
    const float* __restrict__ H, const float* __restrict__ avs, const float* __restrict__ avd,
    float* __restrict__ als, float* __restrict__ ald, int Hh)
{
    __shared__ float ps[2][4], pd[2][4];
    const int tid = threadIdx.x;
    const int ln  = tid & 127;
    const int nl  = tid >> 7;
    const int node = blockIdx.x * 2 + nl;
    const float v = H[(size_t)node * HID + ln];
    float s = v * avs[ln];
    float d = v * avd[ln];
    for (int off = 16; off; off >>= 1) {
        s += __shfl_down(s, off);
        d += __shfl_down(d, off);
    }
    if ((tid & 31) == 0) { ps[nl][ln >> 5] = s; pd[nl][ln >> 5] = d; }
    __syncthreads();
    if (ln < Hh) {
        if (Hh == 4) {
            als[node*4 + ln] = ps[nl][ln];
            ald[node*4 + ln] = pd[nl][ln];
        } else {
            als[node] = ps[nl][0] + ps[nl][1] + ps[nl][2] + ps[nl][3];
            ald[node] = pd[nl][0] + pd[nl][1] + pd[nl][2] + pd[nl][3];
        }
    }
}

// ---------------- CSR build ----------------
__global__ void hist_kernel(const int* __restrict__ ei, int* __restrict__ counts) {
    int e = blockIdx.x * blockDim.x + threadIdx.x;
    if (e >= N_ETOT) return;
    int dst = (e < N_EDGES) ? ei[N_EDGES + e] : e - N_EDGES;
    atomicAdd(&counts[dst], 1);
}

__global__ __launch_bounds__(256) void scanA_kernel(
    const int* __restrict__ counts, int* __restrict__ rowptr, int* __restrict__ bsum)
{
    __shared__ int ls[256];
    const int t = threadIdx.x;
    const int i = blockIdx.x * 256 + t;
    const int v = (i < N_NODES) ? counts[i] : 0;
    ls[t] = v; __syncthreads();
    #pragma unroll
    for (int off = 1; off < 256; off <<= 1) {
        int add = (t >= off) ? ls[t - off] : 0;
        __syncthreads();
        ls[t] += add;
        __syncthreads();
    }
    if (i < N_NODES) rowptr[i] = ls[t] - v;   // exclusive within block
    if (t == 255) bsum[blockIdx.x] = ls[255];
}

__global__ __launch_bounds__(512) void scanB_kernel(int* __restrict__ bsum)
{
    __shared__ int ls[512];
    const int t = threadIdx.x;
    const int v = (t < NBLK_SCAN) ? bsum[t] : 0;
    ls[t] = v; __syncthreads();
    #pragma unroll
    for (int off = 1; off < 512; off <<= 1) {
        int add = (t >= off) ? ls[t - off] : 0;
        __syncthreads();
        ls[t] += add;
        __syncthreads();
    }
    if (t < NBLK_SCAN) bsum[t] = ls[t] - v;   // exclusive
}

__global__ void scanC_kernel(int* __restrict__ rowptr, const int* __restrict__ bsum,
                             int* __restrict__ cursor)
{
    int i = blockIdx.x * 256 + threadIdx.x;
    if (i < N_NODES) {
        int v = rowptr[i] + bsum[blockIdx.x];
        rowptr[i] = v;
        cursor[i] = v;
    }
    if (i == 0) rowptr[N_NODES] = N_ETOT;
}

__global__ void scatter_kernel(const int* __restrict__ ei, int* __restrict__ cursor,
                               int* __restrict__ psrc)
{
    int e = blockIdx.x * blockDim.x + threadIdx.x;
    if (e >= N_ETOT) return;
    int src, dst;
    if (e < N_EDGES) { src = ei[e]; dst = ei[N_EDGES + e]; }
    else             { src = dst = e - N_EDGES; }
    int pos = atomicAdd(&cursor[dst], 1);
    psrc[pos] = src;
}

// ---------------- fused softmax + aggregation: one wave per dst node ----------------
template<int HH>
__global__ __launch_bounds__(256) void agg_kernel(
    const float* __restrict__ H, const float* __restrict__ als,
    const float* __restrict__ ald, const int* __restrict__ rowptr,
    const int* __restrict__ psrc, float* __restrict__ Out)
{
    const int tid  = threadIdx.x;
    const int node = blockIdx.x * 4 + (tid >> 6);
    if (node >= N_NODES) return;
    const int lane = tid & 63;
    const int r0 = rowptr[node];
    const int r1 = rowptr[node + 1];

    float accA = 0.f, accB = 0.f;

    if constexpr (HH == 4) {
        const float4 d4 = *(const float4*)&ald[node * 4];
        const bool hi = (lane & 32) != 0;
        const float aldA = hi ? d4.y : d4.x;
        const float aldB = hi ? d4.w : d4.z;
        float denA = 0.f, denB = 0.f;
        for (int p = r0; p < r1; ++p) {
            const int src = psrc[p];
            const float4 s4 = *(const float4*)&als[src * 4];
            float vA = (hi ? s4.y : s4.x) + aldA;
            float vB = (hi ? s4.w : s4.z) + aldB;
            vA = vA > 0.f ? vA : 0.2f * vA;
            vB = vB > 0.f ? vB : 0.2f * vB;
            denA += __expf(vA);
            denB += __expf(vB);
        }
        const float invA = 1.f / (denA + 1e-16f);
        const float invB = 1.f / (denB + 1e-16f);
        for (int p = r0; p < r1; ++p) {
            const int src = psrc[p];
            const float4 s4 = *(const float4*)&als[src * 4];
            float vA = (hi ? s4.y : s4.x) + aldA;
            float vB = (hi ? s4.w : s4.z) + aldB;
            vA = vA > 0.f ? vA : 0.2f * vA;
            vB = vB > 0.f ? vB : 0.2f * vB;
            const float aA = __expf(vA) * invA;
            const float aB = __expf(vB) * invB;
            accA += aA * H[(size_t)src * HID + lane];
            accB += aB * H[(size_t)src * HID + 64 + lane];
        }
    } else {
        const float dn = ald[node];
        float den = 0.f;
        for (int p = r0; p < r1; ++p) {
            float v = als[psrc[p]] + dn;
            v = v > 0.f ? v : 0.2f * v;
            den += __expf(v);
        }
        const float inv = 1.f / (den + 1e-16f);
        for (int p = r0; p < r1; ++p) {
            const int src = psrc[p];
            float v = als[src] + dn;
            v = v > 0.f ? v : 0.2f * v;
            const float a = __expf(v) * inv;
            accA += a * H[(size_t)src * HID + lane];
            accB += a * H[(size_t)src * HID + 64 + lane];
        }
    }
    Out[(size_t)node * HID + lane]      = accA;
    Out[(size_t)node * HID + 64 + lane] = accB;
}

// ---------------- BN ----------------
__global__ __launch_bounds__(256) void bn_stats_kernel(
    const float* __restrict__ X, float* __restrict__ sums, float* __restrict__ ssq)
{
    __shared__ float ls[256], lq[256];
    int tid = threadIdx.x;
    int c = tid & 127;
    int half = tid >> 7;
    int rpb = (N_NODES + gridDim.x - 1) / gridDim.x;
    int r0 = blockIdx.x * rpb;
    int r1 = min(r0 + rpb, N_NODES);
    float s = 0.f, q = 0.f;
    for (int r = r0 + half; r < r1; r += 2) {
        float v = X[(size_t)r * HID + c];
        s += v; q += v * v;
    }
    ls[tid] = s; lq[tid] = q;
    __syncthreads();
    if (half == 0) {
        atomicAdd(&sums[c], ls[tid] + ls[tid + 128]);
        atomicAdd(&ssq[c],  lq[tid] + lq[tid + 128]);
    }
}

__global__ void bn_finalize_kernel(
    const float* __restrict__ sums, const float* __restrict__ ssq,
    const float* __restrict__ g, const float* __restrict__ be,
    float* __restrict__ scale, float* __restrict__ shift)
{
    int c = threadIdx.x;
    float m = sums[c] * (1.f / N_NODES);
    float v = ssq[c] * (1.f / N_NODES) - m * m;
    float sc = g[c] * rsqrtf(v + 1e-5f);
    scale[c] = sc;
    shift[c] = be[c] - m * sc;
}

__global__ void bn_apply_kernel(
    float* __restrict__ X, const float* __restrict__ scale, const float* __restrict__ shift)
{
    int i = blockIdx.x * blockDim.x + threadIdx.x;
    if (i >= N_NODES * HID) return;
    int c = i & 127;
    float v = X[i] * scale[c] + shift[c];
    X[i] = (v > 0.f) ? v : 0.f;
}

// layer 3: BN+ReLU fused directly into pooling (no write-back of X needed)
__global__ void bn_apply_pool_kernel(
    const float* __restrict__ X, const float* __restrict__ scale, const float* __restrict__ shift,
    const int* __restrict__ batch, float* __restrict__ pooled, float* __restrict__ cnt)
{
    int i = blockIdx.x * blockDim.x + threadIdx.x;
    if (i >= N_NODES * HID) return;
    int c = i & 127;
    int n = i >> 7;
    float v = X[i] * scale[c] + shift[c];
    v = (v > 0.f) ? v : 0.f;
    int g = batch[n];
    atomicAdd(&pooled[(size_t)g * HID + c], v);
    if (c == 0) atomicAdd(&cnt[g], 1.0f);
}

// ---------------- MLP head ----------------
__global__ __launch_bounds__(64) void mlp_kernel(
    const float* __restrict__ pooled, const float* __restrict__ cnt,
    const float* __restrict__ fw1, const float* __restrict__ fb1,
    const float* __restrict__ fw2, const float* __restrict__ fb2,
    float* __restrict__ out)
{
    __shared__ float row[HID];
    int g = blockIdx.x;
    int j = threadIdx.x;
    float inv = 1.0f / fmaxf(cnt[g], 1.0f);
    row[j]      = pooled[(size_t)g * HID + j] * inv;
    row[j + 64] = pooled[(size_t)g * HID + 64 + j] * inv;
    __syncthreads();
    float z = fb1[j];
    for (int c = 0; c < HID; ++c) z += row[c] * fw1[c * 64 + j];
    z = fmaxf(z, 0.f);
    float p = z * fw2[j];
    for (int off = 32; off > 0; off >>= 1) p += __shfl_down(p, off);
    if (j == 0) out[g] = p + fb2[0];
}

// ---------------- host ----------------
extern "C" void kernel_launch(void* const* d_in, const int* in_sizes, int n_in,
                              void* d_out, int out_size, void* d_ws, size_t ws_size,
                              hipStream_t stream)
{
    const float* x     = (const float*)d_in[0];
    const int*   ei    = (const int*)d_in[1];
    const int*   batch = (const int*)d_in[2];
    const float* W1  = (const float*)d_in[3];
    const float* as1 = (const float*)d_in[4];
    const float* ad1 = (const float*)d_in[5];
    const float* g1  = (const float*)d_in[7];
    const float* be1 = (const float*)d_in[8];
    const float* W2  = (const float*)d_in[9];
    const float* as2 = (const float*)d_in[10];
    const float* ad2 = (const float*)d_in[11];
    const float* g2  = (const float*)d_in[13];
    const float* be2 = (const float*)d_in[14];
    const float* W3  = (const float*)d_in[15];
    const float* as3 = (const float*)d_in[16];
    const float* ad3 = (const float*)d_in[17];
    const float* g3  = (const float*)d_in[19];
    const float* be3 = (const float*)d_in[20];
    const float* fw1 = (const float*)d_in[21];
    const float* fb1 = (const float*)d_in[22];
    const float* fw2 = (const float*)d_in[23];
    const float* fb2 = (const float*)d_in[24];
    float* out = (float*)d_out;

    float* ws = (float*)d_ws;
    const size_t NH = (size_t)N_NODES * HID;
    float* A      = ws;
    float* B      = A + NH;
    float* als    = B + NH;
    float* ald    = als + (size_t)N_NODES * 4;
    float* sums   = ald + (size_t)N_NODES * 4;
    float* ssq    = sums + HID;
    float* scale  = ssq + HID;
    float* shift  = scale + HID;
    float* pooled = shift + HID;
    float* cnt    = pooled + (size_t)NGRAPH * HID;
    int*   rowptr = (int*)(cnt + NGRAPH);
    int*   counts = rowptr + (N_NODES + 1);
    int*   cursor = counts + N_NODES;
    int*   bsum   = cursor + N_NODES;
    int*   psrc   = bsum + 512;

    auto cdiv = [](int a, int b) { return (a + b - 1) / b; };

    // ---- CSR build (once; graph shared by all layers) ----
    hipMemsetAsync(counts, 0, (size_t)N_NODES * sizeof(int), stream);
    hist_kernel<<<cdiv(N_ETOT, 256), 256, 0, stream>>>(ei, counts);
    scanA_kernel<<<NBLK_SCAN, 256, 0, stream>>>(counts, rowptr, bsum);
    scanB_kernel<<<1, 512, 0, stream>>>(bsum);
    scanC_kernel<<<NBLK_SCAN, 256, 0, stream>>>(rowptr, bsum, cursor);
    scatter_kernel<<<cdiv(N_ETOT, 256), 256, 0, stream>>>(ei, cursor, psrc);

    auto layer = [&](const float* in, const float* W, const float* avs, const float* avd,
                     const float* g, const float* be, int Hh, int K, bool last)
    {
        if (K == 128)
            gemm128_kernel<128><<<cdiv(N_NODES,128), 256, 0, stream>>>(in, W, A, N_NODES);
        else
            gemm128_kernel<22><<<cdiv(N_NODES,128), 256, 0, stream>>>(in, W, A, N_NODES);
        scores_kernel<<<cdiv(N_NODES,2), 256, 0, stream>>>(A, avs, avd, als, ald, Hh);
        if (Hh == 4)
            agg_kernel<4><<<cdiv(N_NODES,4), 256, 0, stream>>>(A, als, ald, rowptr, psrc, B);
        else
            agg_kernel<1><<<cdiv(N_NODES,4), 256, 0, stream>>>(A, als, ald, rowptr, psrc, B);
        hipMemsetAsync(sums, 0, 2 * HID * sizeof(float), stream);
        bn_stats_kernel<<<256, 256, 0, stream>>>(B, sums, ssq);
        bn_finalize_kernel<<<1, 128, 0, stream>>>(sums, ssq, g, be, scale, shift);
        if (!last) {
            bn_apply_kernel<<<cdiv(N_NODES * HID, 256), 256, 0, stream>>>(B, scale, shift);
        } else {
            hipMemsetAsync(pooled, 0, ((size_t)NGRAPH * HID + NGRAPH) * sizeof(float), stream);
            bn_apply_pool_kernel<<<cdiv(N_NODES * HID, 256), 256, 0, stream>>>(
                B, scale, shift, batch, pooled, cnt);
        }
    };

    layer(x, W1, as1, ad1, g1, be1, 4, 22,  false);
    layer(B, W2, as2, ad2, g2, be2, 4, 128, false);
    layer(B, W3, as3, ad3, g3, be3, 1, 128, true);

    mlp_kernel<<<NGRAPH, 64, 0, stream>>>(pooled, cnt, fw1, fb1, fw2, fb2, out);
}

// Round 4
// 650.358 us; speedup vs baseline: 2.6792x; 1.3875x over previous
//
#include <hip/hip_runtime.h>

#define N_NODES 100000
#define N_EDGES 300000
#define N_ETOT  400000   // E + N self-loops
#define NGRAPH  4096
#define HID     128
#define NBLK_SCAN 391    // cdiv(N_NODES, 256)
#define PNPB    128      // nodes per block in pool

// ---------------- GEMM + fused input-BN + fused attention scores ----------------
// C[M,128] = act(A)[M,K] @ W[K,128], where act = BN(scale,shift)+ReLU if PRE_BN.
// Epilogue computes als/ald (per-head score reductions) from the accumulators.
template<int K, bool PRE_BN, int HH>
__global__ __launch_bounds__(256) void gemm_kernel(
    const float* __restrict__ A, const float* __restrict__ W,
    const float* __restrict__ scale, const float* __restrict__ shift,
    const float* __restrict__ avs, const float* __restrict__ avd,
    float* __restrict__ C, float* __restrict__ als, float* __restrict__ ald, int M)
{
    __shared__ float smem[2][32][HID];   // 32 KB: Al/Wl during loop, ps/pd in epilogue
    auto Al = smem[0];   // [k][row]
    auto Wl = smem[1];   // [k][col]
    const int tid = threadIdx.x;
    const int tx = tid & 15;
    const int ty = tid >> 4;
    const int row0 = blockIdx.x * 128;

    float acc[2][2][4][4];
    #pragma unroll
    for (int a = 0; a < 2; ++a)
      #pragma unroll
      for (int b = 0; b < 2; ++b)
        #pragma unroll
        for (int i = 0; i < 4; ++i)
          #pragma unroll
          for (int j = 0; j < 4; ++j) acc[a][b][i][j] = 0.f;

    for (int k0 = 0; k0 < K; k0 += 32) {
        {   // stage W
            const int k  = tid >> 3;
            const int c0 = (tid & 7) * 4;
            if (k0 + k < K) {
                #pragma unroll
                for (int q = 0; q < 4; ++q)
                    *(float4*)&Wl[k][c0 + 32*q] =
                        *(const float4*)&W[(size_t)(k0 + k)*HID + c0 + 32*q];
            } else {
                #pragma unroll
                for (int q = 0; q < 4; ++q)
                    *(float4*)&Wl[k][c0 + 32*q] = make_float4(0.f,0.f,0.f,0.f);
            }
        }
        {   // stage A (transposed), optionally BN+ReLU on the fly
            const int r    = tid >> 1;
            const int kh   = (tid & 1) * 16;
            const int grow = row0 + r;
            if constexpr (K % 32 == 0) {
                if (grow < M) {
                    #pragma unroll
                    for (int q = 0; q < 4; ++q) {
                        float4 v = *(const float4*)&A[(size_t)grow*K + k0 + kh + 4*q];
                        if constexpr (PRE_BN) {
                            const int kk = k0 + kh + 4*q;
                            v.x = fmaxf(v.x * scale[kk+0] + shift[kk+0], 0.f);
                            v.y = fmaxf(v.y * scale[kk+1] + shift[kk+1], 0.f);
                            v.z = fmaxf(v.z * scale[kk+2] + shift[kk+2], 0.f);
                            v.w = fmaxf(v.w * scale[kk+3] + shift[kk+3], 0.f);
                        }
                        Al[kh+4*q+0][r] = v.x;
                        Al[kh+4*q+1][r] = v.y;
                        Al[kh+4*q+2][r] = v.z;
                        Al[kh+4*q+3][r] = v.w;
                    }
                } else {
                    #pragma unroll
                    for (int q = 0; q < 16; ++q) Al[kh+q][r] = 0.f;
                }
            } else {
                #pragma unroll
                for (int q = 0; q < 16; ++q) {
                    const int k = kh + q;
                    float v = 0.f;
                    if (grow < M && k0 + k < K) {
                        v = A[(size_t)grow*K + k0 + k];
                        if constexpr (PRE_BN)
                            v = fmaxf(v * scale[k0+k] + shift[k0+k], 0.f);
                    }
                    Al[k][r] = v;
                }
            }
        }
        __syncthreads();
        #pragma unroll 4
        for (int k = 0; k < 32; ++k) {
            const float4 a0 = *(const float4*)&Al[k][ty*4];
            const float4 a1 = *(const float4*)&Al[k][64 + ty*4];
            const float4 w0 = *(const float4*)&Wl[k][tx*4];
            const float4 w1 = *(const float4*)&Wl[k][64 + tx*4];
            const float av[2][4] = {{a0.x,a0.y,a0.z,a0.w},{a1.x,a1.y,a1.z,a1.w}};
            const float wv[2][4] = {{w0.x,w0.y,w0.z,w0.w},{w1.x,w1.y,w1.z,w1.w}};
            #pragma unroll
            for (int rh = 0; rh < 2; ++rh)
              #pragma unroll
              for (int ch = 0; ch < 2; ++ch)
                #pragma unroll
                for (int i = 0; i < 4; ++i)
                  #pragma unroll
                  for (int j = 0; j < 4; ++j)
                      acc[rh][ch][i][j] += av[rh][i] * wv[ch][j];
        }
        __syncthreads();
    }

    // ---- C write ----
    #pragma unroll
    for (int rh = 0; rh < 2; ++rh)
      #pragma unroll
      for (int i = 0; i < 4; ++i) {
        const int grow = row0 + rh*64 + ty*4 + i;
        if (grow < M) {
            #pragma unroll
            for (int ch = 0; ch < 2; ++ch)
                *(float4*)&C[(size_t)grow*HID + ch*64 + tx*4] =
                    make_float4(acc[rh][ch][i][0], acc[rh][ch][i][1],
                                acc[rh][ch][i][2], acc[rh][ch][i][3]);
        }
      }

    // ---- fused attention scores: als/ald ----
    float* ps = &smem[0][0][0];   // [ch][row][tx] = [2][128][16]
    float* pd = &smem[1][0][0];
    #pragma unroll
    for (int rh = 0; rh < 2; ++rh)
      #pragma unroll
      for (int i = 0; i < 4; ++i) {
        const int rl = rh*64 + ty*4 + i;
        #pragma unroll
        for (int ch = 0; ch < 2; ++ch) {
            float s = 0.f, d = 0.f;
            #pragma unroll
            for (int j = 0; j < 4; ++j) {
                const int col = ch*64 + tx*4 + j;
                s += acc[rh][ch][i][j] * avs[col];
                d += acc[rh][ch][i][j] * avd[col];
            }
            ps[(ch*128 + rl)*16 + tx] = s;
            pd[(ch*128 + rl)*16 + tx] = d;
        }
      }
    __syncthreads();
    {
        const int row  = tid & 127;
        const float* buf  = (tid < 128) ? ps : pd;
        float*       outp = (tid < 128) ? als : ald;
        const int grow = row0 + row;
        if (grow < M) {
            if constexpr (HH == 4) {
                #pragma unroll
                for (int h = 0; h < 4; ++h) {
                    const int ch = h >> 1;
                    const int q0 = (h & 1) * 8;
                    float s = 0.f;
                    #pragma unroll
                    for (int q = 0; q < 8; ++q) s += buf[(ch*128 + row)*16 + q0 + q];
                    outp[grow*4 + h] = s;
                }
            } else {
                float s = 0.f;
                #pragma unroll
                for (int ch = 0; ch < 2; ++ch)
                    #pragma unroll
                    for (int q = 0; q < 16; ++q) s += buf[(ch*128 + row)*16 + q];
                outp[grow] = s;
            }
        }
    }
}

// ---------------- CSR build ----------------
__global__ void hist_kernel(const int* __restrict__ ei, int* __restrict__ counts) {
    int e = blockIdx.x * blockDim.x + threadIdx.x;
    if (e >= N_ETOT) return;
    int dst = (e < N_EDGES) ? ei[N_EDGES + e] : e - N_EDGES;
    atomicAdd(&counts[dst], 1);
}

__global__ __launch_bounds__(256) void scanA_kernel(
    const int* __restrict__ counts, int* __restrict__ rowptr, int* __restrict__ bsum)
{
    __shared__ int ls[256];
    const int t = threadIdx.x;
    const int i = blockIdx.x * 256 + t;
    const int v = (i < N_NODES) ? counts[i] : 0;
    ls[t] = v; __syncthreads();
    #pragma unroll
    for (int off = 1; off < 256; off <<= 1) {
        int add = (t >= off) ? ls[t - off] : 0;
        __syncthreads();
        ls[t] += add;
        __syncthreads();
    }
    if (i < N_NODES) rowptr[i] = ls[t] - v;
    if (t == 255) bsum[blockIdx.x] = ls[255];
}

__global__ __launch_bounds__(512) void scanB_kernel(int* __restrict__ bsum)
{
    __shared__ int ls[512];
    const int t = threadIdx.x;
    const int v = (t < NBLK_SCAN) ? bsum[t] : 0;
    ls[t] = v; __syncthreads();
    #pragma unroll
    for (int off = 1; off < 512; off <<= 1) {
        int add = (t >= off) ? ls[t - off] : 0;
        __syncthreads();
        ls[t] += add;
        __syncthreads();
    }
    if (t < NBLK_SCAN) bsum[t] = ls[t] - v;
}

__global__ void scanC_kernel(int* __restrict__ rowptr, const int* __restrict__ bsum,
                             int* __restrict__ cursor)
{
    int i = blockIdx.x * 256 + threadIdx.x;
    if (i < N_NODES) {
        int v = rowptr[i] + bsum[blockIdx.x];
        rowptr[i] = v;
        cursor[i] = v;
    }
    if (i == 0) rowptr[N_NODES] = N_ETOT;
}

__global__ void scatter_kernel(const int* __restrict__ ei, int* __restrict__ cursor,
                               int* __restrict__ psrc)
{
    int e = blockIdx.x * blockDim.x + threadIdx.x;
    if (e >= N_ETOT) return;
    int src, dst;
    if (e < N_EDGES) { src = ei[e]; dst = ei[N_EDGES + e]; }
    else             { src = dst = e - N_EDGES; }
    int pos = atomicAdd(&cursor[dst], 1);
    psrc[pos] = src;
}

// ---------------- single-pass softmax aggregation: one wave per dst node ----------------
// out[dst] = (sum_e ex_e * h[src_e]) / (sum_e ex_e + 1e-16)
template<int HH>
__global__ __launch_bounds__(256) void agg_kernel(
    const float* __restrict__ H, const float* __restrict__ als,
    const float* __restrict__ ald, const int* __restrict__ rowptr,
    const int* __restrict__ psrc, float* __restrict__ Out)
{
    const int tid  = threadIdx.x;
    const int node = blockIdx.x * 4 + (tid >> 6);
    if (node >= N_NODES) return;
    const int lane = tid & 63;
    const int r0 = rowptr[node];
    const int r1 = rowptr[node + 1];

    float den = 0.f;
    float2 acc = make_float2(0.f, 0.f);

    if constexpr (HH == 4) {
        const int hd = lane >> 4;                 // head of channels 2*lane, 2*lane+1
        const float aldh = ald[node*4 + hd];
        for (int p = r0; p < r1; ++p) {
            const int src = psrc[p];
            float v = als[src*4 + hd] + aldh;
            v = (v > 0.f) ? v : 0.2f * v;
            const float ex = __expf(v);
            const float2 h2 = *(const float2*)&H[(size_t)src * HID + lane*2];
            acc.x += ex * h2.x;
            acc.y += ex * h2.y;
            den   += ex;
        }
    } else {
        const float aldh = ald[node];
        for (int p = r0; p < r1; ++p) {
            const int src = psrc[p];
            float v = als[src] + aldh;
            v = (v > 0.f) ? v : 0.2f * v;
            const float ex = __expf(v);
            const float2 h2 = *(const float2*)&H[(size_t)src * HID + lane*2];
            acc.x += ex * h2.x;
            acc.y += ex * h2.y;
            den   += ex;
        }
    }
    const float inv = 1.f / (den + 1e-16f);
    *(float2*)&Out[(size_t)node * HID + lane*2] = make_float2(acc.x * inv, acc.y * inv);
}

// ---------------- BN stats ----------------
__global__ __launch_bounds__(256) void bn_stats_kernel(
    const float* __restrict__ X, float* __restrict__ sums, float* __restrict__ ssq)
{
    __shared__ float ls[256], lq[256];
    int tid = threadIdx.x;
    int c = tid & 127;
    int half = tid >> 7;
    int rpb = (N_NODES + gridDim.x - 1) / gridDim.x;
    int r0 = blockIdx.x * rpb;
    int r1 = min(r0 + rpb, N_NODES);
    float s = 0.f, q = 0.f;
    for (int r = r0 + half; r < r1; r += 2) {
        float v = X[(size_t)r * HID + c];
        s += v; q += v * v;
    }
    ls[tid] = s; lq[tid] = q;
    __syncthreads();
    if (half == 0) {
        atomicAdd(&sums[c], ls[tid] + ls[tid + 128]);
        atomicAdd(&ssq[c],  lq[tid] + lq[tid + 128]);
    }
}

__global__ void bn_finalize_kernel(
    const float* __restrict__ sums, const float* __restrict__ ssq,
    const float* __restrict__ g, const float* __restrict__ be,
    float* __restrict__ scale, float* __restrict__ shift)
{
    int c = threadIdx.x;
    float m = sums[c] * (1.f / N_NODES);
    float v = ssq[c] * (1.f / N_NODES) - m * m;
    float sc = g[c] * rsqrtf(v + 1e-5f);
    scale[c] = sc;
    shift[c] = be[c] - m * sc;
}

// ---------------- layer-3 BN+ReLU fused pool (run-accumulating; batch is sorted) ----------------
__global__ __launch_bounds__(128) void bn_pool_kernel(
    const float* __restrict__ X, const float* __restrict__ scale, const float* __restrict__ shift,
    const int* __restrict__ batch, float* __restrict__ pooled, float* __restrict__ cnt)
{
    const int c = threadIdx.x;
    const int n0 = blockIdx.x * PNPB;
    const int n1 = min(n0 + PNPB, N_NODES);
    const float sc = scale[c], sh = shift[c];
    int gcur = batch[n0];
    float acc = 0.f;
    int run = 0;
    for (int n = n0; n < n1; ++n) {
        const int g = batch[n];          // uniform per block -> broadcast
        if (g != gcur) {
            atomicAdd(&pooled[(size_t)gcur * HID + c], acc);
            if (c == 0) atomicAdd(&cnt[gcur], (float)run);
            acc = 0.f; run = 0; gcur = g;
        }
        const float v = X[(size_t)n * HID + c] * sc + sh;
        acc += fmaxf(v, 0.f);
        ++run;
    }
    atomicAdd(&pooled[(size_t)gcur * HID + c], acc);
    if (c == 0) atomicAdd(&cnt[gcur], (float)run);
}

// ---------------- MLP head: fw1 staged in LDS, 16 graphs per block ----------------
__global__ __launch_bounds__(256) void mlp_kernel(
    const float* __restrict__ pooled, const float* __restrict__ cnt,
    const float* __restrict__ fw1, const float* __restrict__ fb1,
    const float* __restrict__ fw2, const float* __restrict__ fb2,
    float* __restrict__ out)
{
    __shared__ float w1[HID * 64];   // 32 KB
    __shared__ float rows[4][HID];
    const int tid = threadIdx.x;
    for (int i = tid; i < HID * 64; i += 256) w1[i] = fw1[i];
    const int gl = tid >> 6;   // graph slot 0..3 (= wave id)
    const int j  = tid & 63;
    const float b1 = fb1[j];
    const float w2 = fw2[j];
    __syncthreads();
    #pragma unroll
    for (int it = 0; it < 4; ++it) {
        const int g = blockIdx.x * 16 + it * 4 + gl;
        const float inv = 1.f / fmaxf(cnt[g], 1.f);
        rows[gl][j]      = pooled[(size_t)g * HID + j] * inv;
        rows[gl][j + 64] = pooled[(size_t)g * HID + 64 + j] * inv;
        __syncthreads();
        float z = b1;
        #pragma unroll 8
        for (int c2 = 0; c2 < HID; ++c2) z += rows[gl][c2] * w1[c2 * 64 + j];
        z = fmaxf(z, 0.f);
        float p = z * w2;
        #pragma unroll
        for (int off = 32; off; off >>= 1) p += __shfl_down(p, off);
        if (j == 0) out[g] = p + fb2[0];
        __syncthreads();
    }
}

// ---------------- host ----------------
extern "C" void kernel_launch(void* const* d_in, const int* in_sizes, int n_in,
                              void* d_out, int out_size, void* d_ws, size_t ws_size,
                              hipStream_t stream)
{
    const float* x     = (const float*)d_in[0];
    const int*   ei    = (const int*)d_in[1];
    const int*   batch = (const int*)d_in[2];
    const float* W1  = (const float*)d_in[3];
    const float* as1 = (const float*)d_in[4];
    const float* ad1 = (const float*)d_in[5];
    const float* g1  = (const float*)d_in[7];
    const float* be1 = (const float*)d_in[8];
    const float* W2  = (const float*)d_in[9];
    const float* as2 = (const float*)d_in[10];
    const float* ad2 = (const float*)d_in[11];
    const float* g2  = (const float*)d_in[13];
    const float* be2 = (const float*)d_in[14];
    const float* W3  = (const float*)d_in[15];
    const float* as3 = (const float*)d_in[16];
    const float* ad3 = (const float*)d_in[17];
    const float* g3  = (const float*)d_in[19];
    const float* be3 = (const float*)d_in[20];
    const float* fw1 = (const float*)d_in[21];
    const float* fb1 = (const float*)d_in[22];
    const float* fw2 = (const float*)d_in[23];
    const float* fb2 = (const float*)d_in[24];
    float* out = (float*)d_out;

    float* ws = (float*)d_ws;
    const size_t NH = (size_t)N_NODES * HID;
    float* A      = ws;
    float* B      = A + NH;
    float* als    = B + NH;
    float* ald    = als + (size_t)N_NODES * 4;
    float* sums   = ald + (size_t)N_NODES * 4;
    float* ssq    = sums + HID;
    float* scale  = ssq + HID;
    float* shift  = scale + HID;
    float* pooled = shift + HID;
    float* cnt    = pooled + (size_t)NGRAPH * HID;
    int*   rowptr = (int*)(cnt + NGRAPH);
    int*   counts = rowptr + (N_NODES + 1);
    int*   cursor = counts + N_NODES;
    int*   bsum   = cursor + N_NODES;
    int*   psrc   = bsum + 512;

    auto cdiv = [](int a, int b) { return (a + b - 1) / b; };

    // ---- CSR build (once; graph shared by all layers) ----
    hipMemsetAsync(counts, 0, (size_t)N_NODES * sizeof(int), stream);
    hist_kernel<<<cdiv(N_ETOT, 256), 256, 0, stream>>>(ei, counts);
    scanA_kernel<<<NBLK_SCAN, 256, 0, stream>>>(counts, rowptr, bsum);
    scanB_kernel<<<1, 512, 0, stream>>>(bsum);
    scanC_kernel<<<NBLK_SCAN, 256, 0, stream>>>(rowptr, bsum, cursor);
    scatter_kernel<<<cdiv(N_ETOT, 256), 256, 0, stream>>>(ei, cursor, psrc);

    const int ggrid = cdiv(N_NODES, 128);

    // ---- layer 1: K=22, no input BN, 4 heads ----
    gemm_kernel<22, false, 4><<<ggrid, 256, 0, stream>>>(
        x, W1, nullptr, nullptr, as1, ad1, A, als, ald, N_NODES);
    agg_kernel<4><<<cdiv(N_NODES, 4), 256, 0, stream>>>(A, als, ald, rowptr, psrc, B);
    hipMemsetAsync(sums, 0, 2 * HID * sizeof(float), stream);
    bn_stats_kernel<<<256, 256, 0, stream>>>(B, sums, ssq);
    bn_finalize_kernel<<<1, 128, 0, stream>>>(sums, ssq, g1, be1, scale, shift);

    // ---- layer 2: K=128, input BN(scale/shift)+ReLU fused, 4 heads ----
    gemm_kernel<128, true, 4><<<ggrid, 256, 0, stream>>>(
        B, W2, scale, shift, as2, ad2, A, als, ald, N_NODES);
    agg_kernel<4><<<cdiv(N_NODES, 4), 256, 0, stream>>>(A, als, ald, rowptr, psrc, B);
    hipMemsetAsync(sums, 0, 2 * HID * sizeof(float), stream);
    bn_stats_kernel<<<256, 256, 0, stream>>>(B, sums, ssq);
    bn_finalize_kernel<<<1, 128, 0, stream>>>(sums, ssq, g2, be2, scale, shift);

    // ---- layer 3: K=128, input BN fused, 1 head ----
    gemm_kernel<128, true, 1><<<ggrid, 256, 0, stream>>>(
        B, W3, scale, shift, as3, ad3, A, als, ald, N_NODES);
    agg_kernel<1><<<cdiv(N_NODES, 4), 256, 0, stream>>>(A, als, ald, rowptr, psrc, B);
    hipMemsetAsync(sums, 0, 2 * HID * sizeof(float), stream);
    bn_stats_kernel<<<256, 256, 0, stream>>>(B, sums, ssq);
    bn_finalize_kernel<<<1, 128, 0, stream>>>(sums, ssq, g3, be3, scale, shift);

    // ---- BN+ReLU fused pool, then MLP ----
    hipMemsetAsync(pooled, 0, ((size_t)NGRAPH * HID + NGRAPH) * sizeof(float), stream);
    bn_pool_kernel<<<cdiv(N_NODES, PNPB), 128, 0, stream>>>(B, scale, shift, batch, pooled, cnt);
    mlp_kernel<<<NGRAPH / 16, 256, 0, stream>>>(pooled, cnt, fw1, fb1, fw2, fb2, out);
}